// Round 12
// baseline (113.637 us; speedup 1.0000x reference)
//
#include <hip/hip_runtime.h>
#include <math.h>

#define NB 8
#define NQ 256
#define NK 256
#define DIN 10
#define FDIM 64
#define HIDDEN 256
#define NH 8
#define ROWS_PER_BLK 4

#define FSTRIDE 64    // shorts per feat row; XOR-swizzled 8-short col-blocks
#define HSTRIDE 264   // shorts per h row (256 + 8 pad) -> 528 B

typedef float f32x4 __attribute__((ext_vector_type(4)));
typedef float f32x2 __attribute__((ext_vector_type(2)));
typedef short bf16x8 __attribute__((ext_vector_type(8)));

__device__ __forceinline__ short f2bf(float f) {
    return (short)((__float_as_uint(f) + 0x8000u) >> 16);
}
// pack two floats -> two bf16 in ONE instr (RTNE). a -> low half, b -> high.
__device__ __forceinline__ unsigned cvtpk(float a, float b) {
    unsigned r;
    asm("v_cvt_pk_bf16_f32 %0, %1, %2" : "=v"(r) : "v"(a), "v"(b));
    return r;
}
__device__ __forceinline__ float rcpf(float x) { return __builtin_amdgcn_rcpf(x); }
__device__ __forceinline__ float ex2f(float x) { return __builtin_amdgcn_exp2f(x); }
__device__ __forceinline__ float sqtf(float x) { return __builtin_amdgcn_sqrtf(x); }

__device__ __forceinline__ void four4(float x, float* dst) {
    float s1 = __sinf(x), c1 = __cosf(x);
    float s2 = 2.f * s1 * c1, c2 = 1.f - 2.f * s1 * s1;
    float s4 = 2.f * s2 * c2, c4 = 1.f - 2.f * s2 * s2;
    float s8 = 2.f * s4 * c4, c8 = 1.f - 2.f * s4 * s4;
    dst[0] = s1; dst[1] = s2; dst[2] = s4; dst[3] = s8;
    dst[4] = c1; dst[5] = c2; dst[6] = c4; dst[7] = c8;
}
__device__ __forceinline__ void four2(float x, float* dst) {
    float s1 = __sinf(x), c1 = __cosf(x);
    dst[0] = s1; dst[1] = 2.f * s1 * c1;
    dst[2] = c1; dst[3] = 1.f - 2.f * s1 * s1;
}

// r12 = r5 + G1 software-pipelined ONE CHUNK AHEAD (single change):
//   G1(c+1) is independent of chunk c (reads only feat_s, stable per row),
//   so it is issued between silu(c) and bar1(c). Its MFMA/ds_read stream
//   sits in the same basic block as silu's 64-trans chain -> separate
//   pipes, compiler sinks G1 into the trans shadow. Per-chunk serial path
//   shortens from {G1->silu->bars->G2} to {silu||G1next->bars->G2}.
//   Spill discipline (r3/r6 lesson, r8 precedent): the cross-barrier state
//   is ONE unconditional acc ping-pong buffer, statically indexed via full
//   unroll of the 4-chunk loop (c&1 compile-time). launch_bounds(512,4)
//   grew to 88 VGPR cleanly for r8's unconditional state; peak live-set
//   here ~110-125 < 128 cap.
//   Hazards unchanged vs r5: G1-ahead touches only feat_s (WAR vs next
//   row's feature writes sealed by bar1(c3)+bar2(c3)); h_s scheme intact;
//   no G1 beyond chunk 3 (next row's G1(0) runs after the feature barrier).
// Body otherwise verbatim r5/r11 (proven 50.5us): bias as C-in, packed-f32
// silu, raw rcp/sqrt/exp2-tanh, W2 in regs; W1,b1 x -log2(e), W2 x -ln(2).
__global__ __launch_bounds__(512, 4) void relfeat_mfma_kernel(
    const float* __restrict__ q, const float* __restrict__ k,
    const float* __restrict__ W1, const float* __restrict__ b1,
    const float* __restrict__ W2, const float* __restrict__ b2,
    float* __restrict__ out)
{
    __shared__ __align__(16) short feat_s[NK * FSTRIDE];   // 32768 B
    __shared__ __align__(16) short h_s[64 * HSTRIDE];      // 33792 B

    const int t = threadIdx.x;          // 0..511
    const int wave = t >> 6;            // 0..7
    const int lane15 = t & 15;
    const int quad = (t >> 4) & 3;
    const int p = t & 255;              // pair id for features / staging
    const int half = t >> 8;            // 0/1: which half of features
    const int b = blockIdx.x >> 6;
    const int i0 = (blockIdx.x & 63) * ROWS_PER_BLK;

    // ---- k-row for pair j = p: block-invariant, cache in regs ----
    const float* kp = k + ((size_t)b * NK + p) * DIN;
    const float k0 = kp[0], k3 = kp[3], k4 = kp[4], k5 = kp[5], k6 = kp[6],
                k7 = kp[7], k8 = kp[8];
    const float k_speed = sqtf(k5 * k5 + k6 * k6);   // row-invariant

    // ---- W2 fragments in regs (GEMM2 B-operand), scaled by -ln2 ----
    bf16x8 w2f[8];
    if (wave < 4) {
#pragma unroll
        for (int ks = 0; ks < 8; ++ks) {
            const float* wp = W2 + (size_t)(ks * 32 + quad * 8) * NH + (lane15 & 7);
            bf16x8 v;
#pragma unroll
            for (int e = 0; e < 8; ++e)
                v[e] = f2bf(-0.69314718f * wp[(size_t)e * NH]);
            w2f[ks] = v;
        }
    }

    // ---- W1 fragments (A operand), scaled by -log2e ----
    const int n0 = wave * 32;
    bf16x8 w1f[2][2];
#pragma unroll
    for (int nt = 0; nt < 2; ++nt)
#pragma unroll
        for (int ks = 0; ks < 2; ++ks) {
            const float* wp = W1 + (size_t)(ks * 32 + quad * 8) * HIDDEN
                              + (n0 + nt * 16 + lane15);
            bf16x8 v;
#pragma unroll
            for (int e = 0; e < 8; ++e)
                v[e] = f2bf(-1.44269504f * wp[(size_t)e * HIDDEN]);
            w1f[nt][ks] = v;
        }
    // bias fragment (MFMA C-in at ks=0), scaled by -log2e
    f32x4 b1c[2];
#pragma unroll
    for (int nt = 0; nt < 2; ++nt) {
        float4 bb = *(const float4*)&b1[n0 + nt * 16 + quad * 4];
        b1c[nt] = (f32x4){-1.44269504f * bb.x, -1.44269504f * bb.y,
                          -1.44269504f * bb.z, -1.44269504f * bb.w};
    }
    const float b2v = (lane15 < NH) ? b2[lane15] : 0.f;
    // G2 output pointer base (valid only when lane15 < NH; never deref'd else)
    float* const outp = out + ((size_t)b * NH + (lane15 & 7)) * NQ * NK
                        + wave * 16 + quad * 4;

    const int sw = p & 7;        // feature-store swizzle
    const int swr = lane15 & 7;  // feat B-frag read swizzle
    const f32x2 one2 = {1.f, 1.f};

    // ---- GEMM1' for one 64-pair chunk into acc (bias as C-in) ----
    auto g1 = [&](int p0, f32x4 (&acc)[2][4]) {
#pragma unroll
        for (int mt = 0; mt < 4; ++mt) {
            const int r2 = p0 + mt * 16 + lane15;
            const bf16x8 fb = *(const bf16x8*)
                &feat_s[r2 * FSTRIDE + ((quad ^ swr) * 8)];
            acc[0][mt] = __builtin_amdgcn_mfma_f32_16x16x32_bf16(
                w1f[0][0], fb, b1c[0], 0, 0, 0);
            acc[1][mt] = __builtin_amdgcn_mfma_f32_16x16x32_bf16(
                w1f[1][0], fb, b1c[1], 0, 0, 0);
        }
#pragma unroll
        for (int mt = 0; mt < 4; ++mt) {
            const int r2 = p0 + mt * 16 + lane15;
            const bf16x8 fb = *(const bf16x8*)
                &feat_s[r2 * FSTRIDE + (((4 + quad) ^ swr) * 8)];
#pragma unroll
            for (int nt = 0; nt < 2; ++nt)
                acc[nt][mt] = __builtin_amdgcn_mfma_f32_16x16x32_bf16(
                    w1f[nt][1], fb, acc[nt][mt], 0, 0, 0);
        }
    };
    // ---- silu (scale-folded, packed-f32) acc -> packed bf16 ----
    auto siluf = [&](const f32x4 (&acc)[2][4], uint2 (&pk)[2][4]) {
#pragma unroll
        for (int nt = 0; nt < 2; ++nt)
#pragma unroll
            for (int mt = 0; mt < 4; ++mt) {
                const f32x4 a = acc[nt][mt];     // = -log2e * preact
                const f32x2 a01 = {a[0], a[1]}, a23 = {a[2], a[3]};
                const f32x2 e01 = {ex2f(a[0]), ex2f(a[1])};
                const f32x2 e23 = {ex2f(a[2]), ex2f(a[3])};
                const f32x2 t01 = e01 + one2;    // v_pk_add_f32
                const f32x2 t23 = e23 + one2;
                const f32x2 r01 = {rcpf(t01[0]), rcpf(t01[1])};
                const f32x2 r23 = {rcpf(t23[0]), rcpf(t23[1])};
                const f32x2 s01 = a01 * r01;     // v_pk_mul_f32
                const f32x2 s23 = a23 * r23;     // = -1.4427*silu
                pk[nt][mt].x = cvtpk(s01[0], s01[1]);
                pk[nt][mt].y = cvtpk(s23[0], s23[1]);
            }
    };

    // ================= row loop: 4 query rows =================
#pragma unroll 1
    for (int row = 0; row < ROWS_PER_BLK; ++row) {
        const int i = i0 + row;

        // ---- features for pair (i, j=p): proven math, 2 threads/pair ----
        {
            const float* qp = q + ((size_t)b * NQ + i) * DIN;
            const float q0 = qp[0], q3 = qp[3], q4 = qp[4], q5 = qp[5],
                        q6 = qp[6], q7 = qp[7], q8 = qp[8];

            const float dpx = k3 - q3, dpy = k4 - q4;
            const float dvx = k5 - q5, dvy = k6 - q6;
            const float dist = sqtf(dpx * dpx + dpy * dpy + 1e-6f);

            float feat[32];
            if (half == 0) {
                // c8 {0,1,6,7}: dist4 | inv_dist4 | ttca2+dist2 | team2+dspeed2
                const float inv_dist = rcpf(dist + 0.1f);
                const float dot_dp_dv = dpx * dvx + dpy * dvy;
                const float speed_sq = dvx * dvx + dvy * dvy;
                // tanh(relu(z)) = 1 - 2/(1 + 2^(2*log2e*z)), z >= 0
                const float z = fmaxf(0.f, -dot_dp_dv * rcpf(speed_sq + 1e-6f));
                const float ttca = 1.f - 2.f * rcpf(1.f + ex2f(2.88539008f * z));
                const float q_speed = sqtf(q5 * q5 + q6 * q6);
                const float delta_speed = k_speed - q_speed;
                four4(dist,     feat + 0);
                four4(inv_dist, feat + 8);
                four2(ttca,     feat + 16);
                feat[20] = feat[0]; feat[21] = feat[1];   // four2(dist) reuse
                feat[22] = feat[4]; feat[23] = feat[5];
                const bool st = (q0 == k0);               // same_team constants
                feat[24] = st ? 0.84147098f : 0.f;
                feat[25] = st ? 0.90929743f : 0.f;
                feat[26] = st ? 0.54030231f : 1.f;
                feat[27] = st ? -0.41614684f : 1.f;
                four2(delta_speed, feat + 28);
            } else {
                // c8 {2,3,4,5}: ata4 | aspect4 | dpx2+dpy2 | dvx2+dvy2
                const float inv_d2 = rcpf(dist + 1e-6f);
                const float bear_x = dpx * inv_d2, bear_y = dpy * inv_d2;
                const float ata = bear_x * q7 + bear_y * q8;
                const float aspect = bear_x * k7 + bear_y * k8;
                four4(ata,    feat + 0);
                four4(aspect, feat + 8);
                four2(dpx,    feat + 16);
                four2(dpy,    feat + 20);
                four2(dvx,    feat + 24);
                four2(dvy,    feat + 28);
            }
#pragma unroll
            for (int j = 0; j < 4; ++j) {
                const int c8 = half ? (j + 2) : (j < 2 ? j : j + 4);
                uint4 v;
                v.x = cvtpk(feat[j * 8 + 0], feat[j * 8 + 1]);
                v.y = cvtpk(feat[j * 8 + 2], feat[j * 8 + 3]);
                v.z = cvtpk(feat[j * 8 + 4], feat[j * 8 + 5]);
                v.w = cvtpk(feat[j * 8 + 6], feat[j * 8 + 7]);
                *(uint4*)&feat_s[p * FSTRIDE + ((c8 ^ sw) * 8)] = v;
            }
        }
        __syncthreads();  // feat_s(row) ready

        // ---- 4 chunks, G1 pipelined one chunk ahead (full unroll ->
        //      acc ping-pong statically indexed; rule-#20 compliant) ----
        f32x4 accP[2][2][4];
        g1(0, accP[0]);                 // prologue: G1(chunk 0)
#pragma unroll
        for (int c = 0; c < 4; ++c) {
            const int p0 = c * 64;

            // silu(c) from acc[cur]; then issue G1(c+1) into acc[nxt] --
            // same basic block: trans chain || MFMA/ds_read streams.
            uint2 pk[2][4];
            siluf(accP[c & 1], pk);
            if (c < 3)
                g1(p0 + 64, accP[(c + 1) & 1]);

            __syncthreads();  // barrier#1: h_s(prev) fully consumed

            // only the 8 ds_write_b64 live between the barriers
#pragma unroll
            for (int nt = 0; nt < 2; ++nt)
#pragma unroll
                for (int mt = 0; mt < 4; ++mt) {
                    const int pair = mt * 16 + lane15;
                    const int hbase = n0 + nt * 16 + quad * 4;
                    *(uint2*)&h_s[pair * HSTRIDE + hbase] = pk[nt][mt];
                }
            __syncthreads();  // barrier#2: h_s(c) ready

            // GEMM2: waves 0-3, one 16-pair M-tile each; K=256; W2 in regs
            if (wave < 4) {
                const int pw = wave * 16;
                f32x4 acc2 = (f32x4){b2v, b2v, b2v, b2v};
#pragma unroll
                for (int ks = 0; ks < 8; ++ks) {
                    const bf16x8 ha = *(const bf16x8*)&h_s[(pw + lane15) * HSTRIDE
                                                            + ks * 32 + quad * 8];
                    acc2 = __builtin_amdgcn_mfma_f32_16x16x32_bf16(ha, w2f[ks], acc2, 0, 0, 0);
                }
                if (lane15 < NH) {
                    float* op = outp + (size_t)i * NK + p0;
                    *(float4*)op = make_float4(acc2[0], acc2[1], acc2[2], acc2[3]);
                }
            }
            // no end barrier: next chunk's work (silu of prefetched acc,
            // then G1(c+2) on feat_s) conflicts with nothing before bar1.
        }
    }
}

extern "C" void kernel_launch(void* const* d_in, const int* in_sizes, int n_in,
                              void* d_out, int out_size, void* d_ws, size_t ws_size,
                              hipStream_t stream) {
    const float* q  = (const float*)d_in[0];
    const float* k  = (const float*)d_in[1];
    const float* W1 = (const float*)d_in[2];
    const float* b1 = (const float*)d_in[3];
    const float* W2 = (const float*)d_in[4];
    const float* b2 = (const float*)d_in[5];
    float* out = (float*)d_out;

    dim3 grid(NB * NQ / ROWS_PER_BLK);  // 512 blocks = 2/CU, one dispatch round
    dim3 block(512);                    // 8 waves: 16 waves/CU resident
    relfeat_mfma_kernel<<<grid, block, 0, stream>>>(q, k, W1, b1, W2, b2, out);
}

// Round 13
// 107.712 us; speedup vs baseline: 1.0550x; 1.0550x over previous
//
#include <hip/hip_runtime.h>
#include <math.h>

#define NB 8
#define NQ 256
#define NK 256
#define DIN 10
#define FDIM 64
#define HIDDEN 256
#define NH 8
#define ROWS_PER_BLK 4

#define FSTRIDE 64    // shorts per feat row; XOR-swizzled 8-short col-blocks
#define HSTRIDE 264   // shorts per h row (256 + 8 pad) -> 528 B

typedef float f32x4 __attribute__((ext_vector_type(4)));
typedef float f32x2 __attribute__((ext_vector_type(2)));
typedef short bf16x8 __attribute__((ext_vector_type(8)));

__device__ __forceinline__ short f2bf(float f) {
    return (short)((__float_as_uint(f) + 0x8000u) >> 16);
}
// pack two floats -> two bf16 in ONE instr (RTNE). a -> low half, b -> high.
__device__ __forceinline__ unsigned cvtpk(float a, float b) {
    unsigned r;
    asm("v_cvt_pk_bf16_f32 %0, %1, %2" : "=v"(r) : "v"(a), "v"(b));
    return r;
}
__device__ __forceinline__ float rcpf(float x) { return __builtin_amdgcn_rcpf(x); }
__device__ __forceinline__ float ex2f(float x) { return __builtin_amdgcn_exp2f(x); }
__device__ __forceinline__ float sqtf(float x) { return __builtin_amdgcn_sqrtf(x); }

__device__ __forceinline__ void four4(float x, float* dst) {
    float s1 = __sinf(x), c1 = __cosf(x);
    float s2 = 2.f * s1 * c1, c2 = 1.f - 2.f * s1 * s1;
    float s4 = 2.f * s2 * c2, c4 = 1.f - 2.f * s2 * s2;
    float s8 = 2.f * s4 * c4, c8 = 1.f - 2.f * s4 * s4;
    dst[0] = s1; dst[1] = s2; dst[2] = s4; dst[3] = s8;
    dst[4] = c1; dst[5] = c2; dst[6] = c4; dst[7] = c8;
}
__device__ __forceinline__ void four2(float x, float* dst) {
    float s1 = __sinf(x), c1 = __cosf(x);
    dst[0] = s1; dst[1] = 2.f * s1 * c1;
    dst[2] = c1; dst[3] = 1.f - 2.f * s1 * s1;
}

// FINAL (r13) = EXACT REVERT to r5/r11, the session's best verified kernel
// (50.5us dispatch / 106.9us bench; session start was 113.3us).
// Closing ledger: all real gains were instruction trims on this lineage
// (r2: cvtpk+silu-split+W2-regs; r5: bias-as-C-in, packed-f32 silu, raw
// rcp/sqrt/exp2-tanh). Structural rearrangements all failed:
//   spilled (allocator pins 64 VGPR at 512-thread blocks, spills
//   cross-barrier state): r3 G2-pipeline, r6 feat-overlap, r12 G1-ahead,
//   r9 waves_per_eu(6,8);
//   clean but slower: r8 1-barrier ping-pong @1blk/CU (-10%), r10 3blk/CU
//   de-phasing (-15%); neutral: r1 occupancy x2, r7 feature-overlap.
// Plateau cause: joint {silu trans chain near pipe floor} x {allocator
// won't carry pipeline state across barriers at this block shape} x
// {alternative shapes measured slower}. No pipe >52%; this is a
// dependency-structure plateau, not a HW roofline.
__global__ __launch_bounds__(512, 4) void relfeat_mfma_kernel(
    const float* __restrict__ q, const float* __restrict__ k,
    const float* __restrict__ W1, const float* __restrict__ b1,
    const float* __restrict__ W2, const float* __restrict__ b2,
    float* __restrict__ out)
{
    __shared__ __align__(16) short feat_s[NK * FSTRIDE];   // 32768 B
    __shared__ __align__(16) short h_s[64 * HSTRIDE];      // 33792 B

    const int t = threadIdx.x;          // 0..511
    const int wave = t >> 6;            // 0..7
    const int lane15 = t & 15;
    const int quad = (t >> 4) & 3;
    const int p = t & 255;              // pair id for features / staging
    const int half = t >> 8;            // 0/1: which half of features
    const int b = blockIdx.x >> 6;
    const int i0 = (blockIdx.x & 63) * ROWS_PER_BLK;

    // ---- k-row for pair j = p: block-invariant, cache in regs ----
    const float* kp = k + ((size_t)b * NK + p) * DIN;
    const float k0 = kp[0], k3 = kp[3], k4 = kp[4], k5 = kp[5], k6 = kp[6],
                k7 = kp[7], k8 = kp[8];
    const float k_speed = sqtf(k5 * k5 + k6 * k6);   // row-invariant

    // ---- W2 fragments in regs (GEMM2 B-operand), scaled by -ln2 ----
    bf16x8 w2f[8];
    if (wave < 4) {
#pragma unroll
        for (int ks = 0; ks < 8; ++ks) {
            const float* wp = W2 + (size_t)(ks * 32 + quad * 8) * NH + (lane15 & 7);
            bf16x8 v;
#pragma unroll
            for (int e = 0; e < 8; ++e)
                v[e] = f2bf(-0.69314718f * wp[(size_t)e * NH]);
            w2f[ks] = v;
        }
    }

    // ---- W1 fragments (A operand), scaled by -log2e ----
    const int n0 = wave * 32;
    bf16x8 w1f[2][2];
#pragma unroll
    for (int nt = 0; nt < 2; ++nt)
#pragma unroll
        for (int ks = 0; ks < 2; ++ks) {
            const float* wp = W1 + (size_t)(ks * 32 + quad * 8) * HIDDEN
                              + (n0 + nt * 16 + lane15);
            bf16x8 v;
#pragma unroll
            for (int e = 0; e < 8; ++e)
                v[e] = f2bf(-1.44269504f * wp[(size_t)e * HIDDEN]);
            w1f[nt][ks] = v;
        }
    // bias fragment (MFMA C-in at ks=0), scaled by -log2e
    f32x4 b1c[2];
#pragma unroll
    for (int nt = 0; nt < 2; ++nt) {
        float4 bb = *(const float4*)&b1[n0 + nt * 16 + quad * 4];
        b1c[nt] = (f32x4){-1.44269504f * bb.x, -1.44269504f * bb.y,
                          -1.44269504f * bb.z, -1.44269504f * bb.w};
    }
    const float b2v = (lane15 < NH) ? b2[lane15] : 0.f;
    // G2 output pointer base (valid only when lane15 < NH; never deref'd else)
    float* const outp = out + ((size_t)b * NH + (lane15 & 7)) * NQ * NK
                        + wave * 16 + quad * 4;

    const int sw = p & 7;        // feature-store swizzle
    const int swr = lane15 & 7;  // feat B-frag read swizzle
    const f32x2 one2 = {1.f, 1.f};

    // ================= row loop: 4 query rows =================
#pragma unroll 1
    for (int row = 0; row < ROWS_PER_BLK; ++row) {
        const int i = i0 + row;

        // ---- features for pair (i, j=p): proven math, 2 threads/pair ----
        {
            const float* qp = q + ((size_t)b * NQ + i) * DIN;
            const float q0 = qp[0], q3 = qp[3], q4 = qp[4], q5 = qp[5],
                        q6 = qp[6], q7 = qp[7], q8 = qp[8];

            const float dpx = k3 - q3, dpy = k4 - q4;
            const float dvx = k5 - q5, dvy = k6 - q6;
            const float dist = sqtf(dpx * dpx + dpy * dpy + 1e-6f);

            float feat[32];
            if (half == 0) {
                // c8 {0,1,6,7}: dist4 | inv_dist4 | ttca2+dist2 | team2+dspeed2
                const float inv_dist = rcpf(dist + 0.1f);
                const float dot_dp_dv = dpx * dvx + dpy * dvy;
                const float speed_sq = dvx * dvx + dvy * dvy;
                // tanh(relu(z)) = 1 - 2/(1 + 2^(2*log2e*z)), z >= 0
                const float z = fmaxf(0.f, -dot_dp_dv * rcpf(speed_sq + 1e-6f));
                const float ttca = 1.f - 2.f * rcpf(1.f + ex2f(2.88539008f * z));
                const float q_speed = sqtf(q5 * q5 + q6 * q6);
                const float delta_speed = k_speed - q_speed;
                four4(dist,     feat + 0);
                four4(inv_dist, feat + 8);
                four2(ttca,     feat + 16);
                feat[20] = feat[0]; feat[21] = feat[1];   // four2(dist) reuse
                feat[22] = feat[4]; feat[23] = feat[5];
                const bool st = (q0 == k0);               // same_team constants
                feat[24] = st ? 0.84147098f : 0.f;
                feat[25] = st ? 0.90929743f : 0.f;
                feat[26] = st ? 0.54030231f : 1.f;
                feat[27] = st ? -0.41614684f : 1.f;
                four2(delta_speed, feat + 28);
            } else {
                // c8 {2,3,4,5}: ata4 | aspect4 | dpx2+dpy2 | dvx2+dvy2
                const float inv_d2 = rcpf(dist + 1e-6f);
                const float bear_x = dpx * inv_d2, bear_y = dpy * inv_d2;
                const float ata = bear_x * q7 + bear_y * q8;
                const float aspect = bear_x * k7 + bear_y * k8;
                four4(ata,    feat + 0);
                four4(aspect, feat + 8);
                four2(dpx,    feat + 16);
                four2(dpy,    feat + 20);
                four2(dvx,    feat + 24);
                four2(dvy,    feat + 28);
            }
#pragma unroll
            for (int j = 0; j < 4; ++j) {
                const int c8 = half ? (j + 2) : (j < 2 ? j : j + 4);
                uint4 v;
                v.x = cvtpk(feat[j * 8 + 0], feat[j * 8 + 1]);
                v.y = cvtpk(feat[j * 8 + 2], feat[j * 8 + 3]);
                v.z = cvtpk(feat[j * 8 + 4], feat[j * 8 + 5]);
                v.w = cvtpk(feat[j * 8 + 6], feat[j * 8 + 7]);
                *(uint4*)&feat_s[p * FSTRIDE + ((c8 ^ sw) * 8)] = v;
            }
        }
        __syncthreads();  // feat_s(row) ready

        // ---- 4 chunks of 64 pairs ----
#pragma unroll 1
        for (int c = 0; c < 4; ++c) {
            const int p0 = c * 64;

            // GEMM1': bias rides as C-in on the ks=0 MFMAs
            f32x4 acc[2][4];
#pragma unroll
            for (int mt = 0; mt < 4; ++mt) {
                const int r2 = p0 + mt * 16 + lane15;
                const bf16x8 fb = *(const bf16x8*)
                    &feat_s[r2 * FSTRIDE + ((quad ^ swr) * 8)];
                acc[0][mt] = __builtin_amdgcn_mfma_f32_16x16x32_bf16(
                    w1f[0][0], fb, b1c[0], 0, 0, 0);
                acc[1][mt] = __builtin_amdgcn_mfma_f32_16x16x32_bf16(
                    w1f[1][0], fb, b1c[1], 0, 0, 0);
            }
#pragma unroll
            for (int mt = 0; mt < 4; ++mt) {
                const int r2 = p0 + mt * 16 + lane15;
                const bf16x8 fb = *(const bf16x8*)
                    &feat_s[r2 * FSTRIDE + (((4 + quad) ^ swr) * 8)];
#pragma unroll
                for (int nt = 0; nt < 2; ++nt)
                    acc[nt][mt] = __builtin_amdgcn_mfma_f32_16x16x32_bf16(
                        w1f[nt][1], fb, acc[nt][mt], 0, 0, 0);
            }

            // silu-COMPUTE into regs (no LDS): packed-f32 add/mul
            uint2 pk[2][4];
#pragma unroll
            for (int nt = 0; nt < 2; ++nt)
#pragma unroll
                for (int mt = 0; mt < 4; ++mt) {
                    const f32x4 a = acc[nt][mt];     // = -log2e * preact
                    const f32x2 a01 = {a[0], a[1]}, a23 = {a[2], a[3]};
                    const f32x2 e01 = {ex2f(a[0]), ex2f(a[1])};
                    const f32x2 e23 = {ex2f(a[2]), ex2f(a[3])};
                    const f32x2 t01 = e01 + one2;    // v_pk_add_f32
                    const f32x2 t23 = e23 + one2;
                    const f32x2 r01 = {rcpf(t01[0]), rcpf(t01[1])};
                    const f32x2 r23 = {rcpf(t23[0]), rcpf(t23[1])};
                    const f32x2 s01 = a01 * r01;     // v_pk_mul_f32
                    const f32x2 s23 = a23 * r23;     // = -1.4427*silu
                    pk[nt][mt].x = cvtpk(s01[0], s01[1]);
                    pk[nt][mt].y = cvtpk(s23[0], s23[1]);
                }

            __syncthreads();  // barrier#1: h_s(prev) fully consumed

            // only the 8 ds_write_b64 live between the barriers
#pragma unroll
            for (int nt = 0; nt < 2; ++nt)
#pragma unroll
                for (int mt = 0; mt < 4; ++mt) {
                    const int pair = mt * 16 + lane15;
                    const int hbase = n0 + nt * 16 + quad * 4;
                    *(uint2*)&h_s[pair * HSTRIDE + hbase] = pk[nt][mt];
                }
            __syncthreads();  // barrier#2: h_s(c) ready

            // GEMM2: waves 0-3, one 16-pair M-tile each; K=256; W2 in regs
            if (wave < 4) {
                const int pw = wave * 16;
                f32x4 acc2 = (f32x4){b2v, b2v, b2v, b2v};
#pragma unroll
                for (int ks = 0; ks < 8; ++ks) {
                    const bf16x8 ha = *(const bf16x8*)&h_s[(pw + lane15) * HSTRIDE
                                                            + ks * 32 + quad * 8];
                    acc2 = __builtin_amdgcn_mfma_f32_16x16x32_bf16(ha, w2f[ks], acc2, 0, 0, 0);
                }
                if (lane15 < NH) {
                    float* op = outp + (size_t)i * NK + p0;
                    *(float4*)op = make_float4(acc2[0], acc2[1], acc2[2], acc2[3]);
                }
            }
            // no end barrier: next chunk's GEMM1' touches only feat_s
        }
    }
}

extern "C" void kernel_launch(void* const* d_in, const int* in_sizes, int n_in,
                              void* d_out, int out_size, void* d_ws, size_t ws_size,
                              hipStream_t stream) {
    const float* q  = (const float*)d_in[0];
    const float* k  = (const float*)d_in[1];
    const float* W1 = (const float*)d_in[2];
    const float* b1 = (const float*)d_in[3];
    const float* W2 = (const float*)d_in[4];
    const float* b2 = (const float*)d_in[5];
    float* out = (float*)d_out;

    dim3 grid(NB * NQ / ROWS_PER_BLK);  // 512 blocks = 2/CU, one dispatch round
    dim3 block(512);                    // 8 waves: 16 waves/CU resident
    relfeat_mfma_kernel<<<grid, block, 0, stream>>>(q, k, W1, b1, W2, b2, out);
}